// Round 2
// baseline (515.640 us; speedup 1.0000x reference)
//
#include <hip/hip_runtime.h>
#include <hip/hip_bf16.h>
#include <stdint.h>

// Problem constants (from reference)
namespace {
constexpr int kB = 8, kT = 16, kN = 1000, kF = 16;
constexpr int kE = 16000;
constexpr int kH = 4, kHD = 128;        // H*D = 128
constexpr int kHL = 64, kOUT = 8;
constexpr int kG = kB * kT;             // 128 graphs
constexpr float kNeg = 0.2f;

// Canonical bf16 copies of all float inputs, element offsets:
constexpr size_t CX_X    = 0;                       // 2,048,000
constexpr size_t CX_WG   = CX_X    + 2048000;       // 2048
constexpr size_t CX_ATS  = CX_WG   + 2048;          // 128
constexpr size_t CX_ATD  = CX_ATS  + 128;           // 128
constexpr size_t CX_BG   = CX_ATD  + 128;           // 128
constexpr size_t CX_WIH  = CX_BG   + 128;           // 32768
constexpr size_t CX_WHH  = CX_WIH  + 32768;         // 16384
constexpr size_t CX_BIH  = CX_WHH  + 16384;         // 256
constexpr size_t CX_BHH  = CX_BIH  + 256;           // 256
constexpr size_t CX_WCLF = CX_BHH  + 256;           // 512
constexpr size_t CX_BCLF = CX_WCLF + 512;           // 8
constexpr size_t CX_TOTAL = CX_BCLF + 8;            // 2,100,616 elements

// Workspace byte offsets (256-aligned)
constexpr size_t OFF_FLAG  = 0;                      // int
constexpr size_t OFF_ROW   = 256;                    // int[kN+1]
constexpr size_t OFF_COL   = 4352;                   // int[kE]
constexpr size_t OFF_POOL  = 68608;                  // float[kG*kHD]
constexpr size_t OFF_CANON = 134400;                 // bf16[CX_TOTAL]
constexpr size_t OFF_AS    = 4335872;                // per-chunk region starts here
// per chunk of Gc graphs: a_s Gc*16000 B, a_d Gc*16000 B, xp Gc*256000 B
}

__device__ __forceinline__ float bf2f(unsigned short u) {
    return __uint_as_float(((uint32_t)u) << 16);
}
__device__ __forceinline__ float blo(uint32_t u) { return __uint_as_float(u << 16); }
__device__ __forceinline__ float bhi(uint32_t u) { return __uint_as_float(u & 0xffff0000u); }
__device__ __forceinline__ unsigned short f2bf(float f) {
    uint32_t u = __float_as_uint(f);
    uint32_t r = (u + 0x7fff + ((u >> 16) & 1)) >> 16;
    return (unsigned short)r;
}
__device__ __forceinline__ float sigm(float x) { return 1.f / (1.f + __expf(-x)); }

// ---------------------------------------------------------------------------
// Kernel 0: dtype detector. x ~ N(0,1): if bf16, every short has exponent bits
// in the "normal value" band; if fp32, the low-half shorts are ~uniform bits.
// flag = 1 means inputs are fp32.
// ---------------------------------------------------------------------------
__global__ __launch_bounds__(256) void detect_dtype(const unsigned short* __restrict__ x,
                                                    int* __restrict__ flag) {
    __shared__ int cnt;
    if (threadIdx.x == 0) cnt = 0;
    __syncthreads();
    int local = 0;
    for (int i = threadIdx.x; i < 4096; i += 256) {
        unsigned short u = x[i];
        int ex = (u >> 7) & 0xff;
        if (u == 0 || (ex >= 97 && ex <= 143)) local++;
    }
    atomicAdd(&cnt, local);
    __syncthreads();
    if (threadIdx.x == 0) *flag = (cnt >= (4096 * 8) / 10) ? 0 : 1;
}

// ---------------------------------------------------------------------------
// Kernel 1: normalize all float inputs into canonical bf16 (copy or downcast).
// ---------------------------------------------------------------------------
struct ConvArgs {
    const unsigned short* src[11];
    int n[11];
};
__global__ __launch_bounds__(256) void convert_inputs(ConvArgs a,
                                                      const int* __restrict__ flag,
                                                      unsigned short* __restrict__ canon) {
    const int isf = *flag;
    const int stride = gridDim.x * blockDim.x;
    const int tid = blockIdx.x * blockDim.x + threadIdx.x;
    size_t base = 0;
    for (int s = 0; s < 11; ++s) {
        const int n = a.n[s];
        if (isf) {
            const float* fp = (const float*)a.src[s];
            for (int i = tid; i < n; i += stride) canon[base + i] = f2bf(fp[i]);
        } else {
            const unsigned short* sp = a.src[s];
            for (int i = tid; i < n; i += stride) canon[base + i] = sp[i];
        }
        base += (size_t)n;
    }
}

// ---------------------------------------------------------------------------
// Kernel 2: build CSR (edges sorted by dst). Single block, 1024 threads.
// Self-loops are NOT stored; handled explicitly in aggregation.
// ---------------------------------------------------------------------------
__global__ __launch_bounds__(1024) void build_csr(const int* __restrict__ ei,
                                                  int* __restrict__ row,
                                                  int* __restrict__ col) {
    __shared__ int cnt[1024];
    __shared__ int scan[1024];
    const int t = threadIdx.x;
    cnt[t] = 0;
    __syncthreads();
    const int* dst = ei + kE;
    for (int e = t; e < kE; e += 1024) atomicAdd(&cnt[dst[e]], 1);
    __syncthreads();
    scan[t] = cnt[t];
    __syncthreads();
    for (int s = 1; s < 1024; s <<= 1) {
        int v = (t >= s) ? scan[t - s] : 0;
        __syncthreads();
        scan[t] += v;
        __syncthreads();
    }
    if (t == 0) row[0] = 0;
    if (t < kN) row[t + 1] = scan[t];
    int excl = scan[t] - cnt[t];
    __syncthreads();
    cnt[t] = excl;   // running scatter offsets
    __syncthreads();
    for (int e = t; e < kE; e += 1024) {
        int d0 = dst[e];
        int pos = atomicAdd(&cnt[d0], 1);
        col[pos] = ei[e];  // src
    }
}

// ---------------------------------------------------------------------------
// Kernel 3: xp = x @ W_gat (per graph) + attention scalars a_s, a_d.
// 64 nodes per 256-thread block; 16 blocks per graph; Gc graphs per launch.
// ---------------------------------------------------------------------------
__global__ __launch_bounds__(256) void precompute(
        const unsigned short* __restrict__ x,      // canonical bf16, full tensor
        const unsigned short* __restrict__ Wg,
        const unsigned short* __restrict__ atts,
        const unsigned short* __restrict__ attd,
        unsigned short* __restrict__ xp,           // per-chunk, indexed by g_local
        float* __restrict__ a_s, float* __restrict__ a_d,
        int g0) {
    __shared__ float Wl[kF * kHD];
    __shared__ float asl[kHD], adl[kHD];
    __shared__ float xr[64][kF];
    const int t = threadIdx.x;
    const int gl = blockIdx.x >> 4;      // local graph index within chunk
    const int gg = g0 + gl;              // global graph index (for x)
    const int nb = blockIdx.x & 15;
    for (int i = t; i < kF * kHD; i += 256) Wl[i] = bf2f(Wg[i]);
    if (t < kHD) asl[t] = bf2f(atts[t]);
    else adl[t - kHD] = bf2f(attd[t - kHD]);
    const int n0 = nb * 64;
    const int nn = min(64, kN - n0);
    for (int i = t; i < nn * kF; i += 256)
        xr[i / kF][i % kF] = bf2f(x[(size_t)gg * kN * kF + (size_t)n0 * kF + i]);
    __syncthreads();

    const int c = t & 127;
    const int sub = t >> 7;
    const int h = c >> 5, d = c & 31;
    const float w_s = asl[c], w_d = adl[c];
    for (int ln = sub; ln < nn; ln += 2) {
        const int n = n0 + ln;
        float v = 0.f;
#pragma unroll
        for (int f = 0; f < kF; ++f) v += xr[ln][f] * Wl[f * kHD + c];
        xp[((size_t)gl * kN + n) * kHD + c] = f2bf(v);
        float vs = v * w_s, vd = v * w_d;
#pragma unroll
        for (int s = 16; s >= 1; s >>= 1) {
            vs += __shfl_xor(vs, s, 64);
            vd += __shfl_xor(vd, s, 64);
        }
        if (d == 0) {
            a_s[((size_t)gl * kN + n) * kH + h] = vs;
            a_d[((size_t)gl * kN + n) * kH + h] = vd;
        }
    }
}

// ---------------------------------------------------------------------------
// Kernel 4: per-(graph,node) online-softmax edge aggregation + relu + max-pool.
// One wave per (g_local, n); lane L owns channels 2L, 2L+1 (same head).
// ---------------------------------------------------------------------------
__global__ __launch_bounds__(256) void gat_aggregate(
        const int* __restrict__ row, const int* __restrict__ col,
        const unsigned short* __restrict__ xp,
        const float* __restrict__ a_s, const float* __restrict__ a_d,
        const unsigned short* __restrict__ bg,
        unsigned int* __restrict__ pooled,
        int g0, int Gc) {
    const int wave = (blockIdx.x << 2) + (threadIdx.x >> 6);
    const int lane = threadIdx.x & 63;
    const int gl = wave / kN;
    const int n = wave - gl * kN;
    if (gl >= Gc) return;
    const int h = lane >> 4;

    const size_t gn = (size_t)gl * kN;
    const float ad = a_d[(gn + n) * kH + h];

    // self-loop initializes the online softmax (p = 1 at m = e_self)
    float e0 = a_s[(gn + n) * kH + h] + ad;
    e0 = e0 > 0.f ? e0 : kNeg * e0;
    float m = e0, den = 1.f;
    uint32_t u = ((const uint32_t*)(xp + (gn + n) * kHD))[lane];
    float acc0 = blo(u), acc1 = bhi(u);

    const int r1 = row[n + 1];
    for (int ei = row[n]; ei < r1; ++ei) {
        const int s = col[ei];
        float ev = a_s[(gn + s) * kH + h] + ad;
        ev = ev > 0.f ? ev : kNeg * ev;
        const float nm = fmaxf(m, ev);
        const float sc = __expf(m - nm);
        const float p  = __expf(ev - nm);
        const uint32_t us = ((const uint32_t*)(xp + (gn + s) * kHD))[lane];
        den  = den  * sc + p;
        acc0 = acc0 * sc + p * blo(us);
        acc1 = acc1 * sc + p * bhi(us);
        m = nm;
    }
    const float inv = 1.f / den;
    const int c0 = lane * 2;
    float o0 = fmaxf(acc0 * inv + bf2f(bg[c0]),     0.f);
    float o1 = fmaxf(acc1 * inv + bf2f(bg[c0 + 1]), 0.f);
    const size_t gp = (size_t)(g0 + gl) * kHD;
    atomicMax(pooled + gp + c0,     __float_as_uint(o0));
    atomicMax(pooled + gp + c0 + 1, __float_as_uint(o1));
}

// ---------------------------------------------------------------------------
// Kernel 5: LSTM over T=16 + classifier. One block per batch row b.
// Thread r owns gate-row r; W rows staged in registers (packed bf16).
// ---------------------------------------------------------------------------
__global__ __launch_bounds__(256) void lstm_head(
        const float* __restrict__ pooled,
        const unsigned short* __restrict__ Wih,
        const unsigned short* __restrict__ Whh,
        const unsigned short* __restrict__ bih,
        const unsigned short* __restrict__ bhh,
        const unsigned short* __restrict__ Wclf,
        const unsigned short* __restrict__ bclf,
        const int* __restrict__ flag,
        void* __restrict__ out) {
    const int b = blockIdx.x;
    const int r = threadIdx.x;
    __shared__ float xt[kHD];
    __shared__ float hs[kHL];
    __shared__ float gates[4 * kHL];

    uint32_t wih[64];
    const uint32_t* pw = (const uint32_t*)(Wih + (size_t)r * kHD);
#pragma unroll
    for (int j = 0; j < 64; ++j) wih[j] = pw[j];
    uint32_t whh[32];
    const uint32_t* ph = (const uint32_t*)(Whh + (size_t)r * kHL);
#pragma unroll
    for (int j = 0; j < 32; ++j) whh[j] = ph[j];
    const float bias = bf2f(bih[r]) + bf2f(bhh[r]);

    float c_st = 0.f;
    if (r < kHL) hs[r] = 0.f;
    __syncthreads();

    for (int t = 0; t < kT; ++t) {
        if (r < kHD) xt[r] = pooled[((size_t)b * kT + t) * kHD + r];
        __syncthreads();
        float a0 = 0.f, a1 = 0.f, a2 = 0.f, a3 = 0.f;
#pragma unroll
        for (int j = 0; j < 64; j += 4) {
            uint32_t u0 = wih[j], u1 = wih[j + 1], u2 = wih[j + 2], u3 = wih[j + 3];
            a0 += blo(u0) * xt[2 * j + 0] + bhi(u0) * xt[2 * j + 1];
            a1 += blo(u1) * xt[2 * j + 2] + bhi(u1) * xt[2 * j + 3];
            a2 += blo(u2) * xt[2 * j + 4] + bhi(u2) * xt[2 * j + 5];
            a3 += blo(u3) * xt[2 * j + 6] + bhi(u3) * xt[2 * j + 7];
        }
#pragma unroll
        for (int j = 0; j < 32; j += 4) {
            uint32_t u0 = whh[j], u1 = whh[j + 1], u2 = whh[j + 2], u3 = whh[j + 3];
            a0 += blo(u0) * hs[2 * j + 0] + bhi(u0) * hs[2 * j + 1];
            a1 += blo(u1) * hs[2 * j + 2] + bhi(u1) * hs[2 * j + 3];
            a2 += blo(u2) * hs[2 * j + 4] + bhi(u2) * hs[2 * j + 5];
            a3 += blo(u3) * hs[2 * j + 6] + bhi(u3) * hs[2 * j + 7];
        }
        gates[r] = bias + (a0 + a1) + (a2 + a3);
        __syncthreads();
        if (r < kHL) {
            const float iv = sigm(gates[r]);
            const float fv = sigm(gates[kHL + r]);
            const float gv = tanhf(gates[2 * kHL + r]);
            const float ov = sigm(gates[3 * kHL + r]);
            c_st = fv * c_st + iv * gv;
            hs[r] = ov * tanhf(c_st);
        }
        __syncthreads();
    }
    if (r < kOUT) {
        float acc = bf2f(bclf[r]);
#pragma unroll
        for (int k = 0; k < kHL; ++k) acc += hs[k] * bf2f(Wclf[r * kHL + k]);
        if (*flag) ((float*)out)[b * kOUT + r] = acc;
        else ((__hip_bfloat16*)out)[b * kOUT + r] = __float2bfloat16(acc);
    }
}

// ---------------------------------------------------------------------------
extern "C" void kernel_launch(void* const* d_in, const int* in_sizes, int n_in,
                              void* d_out, int out_size, void* d_ws, size_t ws_size,
                              hipStream_t stream) {
    const int* ei = (const int*)d_in[1];

    char* ws = (char*)d_ws;
    int*            flag   = (int*)(ws + OFF_FLAG);
    int*            row    = (int*)(ws + OFF_ROW);
    int*            colv   = (int*)(ws + OFF_COL);
    unsigned int*   pooled = (unsigned int*)(ws + OFF_POOL);
    unsigned short* canon  = (unsigned short*)(ws + OFF_CANON);

    // canonical bf16 pointers
    unsigned short* cX    = canon + CX_X;
    unsigned short* cWg   = canon + CX_WG;
    unsigned short* cAts  = canon + CX_ATS;
    unsigned short* cAtd  = canon + CX_ATD;
    unsigned short* cBg   = canon + CX_BG;
    unsigned short* cWih  = canon + CX_WIH;
    unsigned short* cWhh  = canon + CX_WHH;
    unsigned short* cBih  = canon + CX_BIH;
    unsigned short* cBhh  = canon + CX_BHH;
    unsigned short* cWclf = canon + CX_WCLF;
    unsigned short* cBclf = canon + CX_BCLF;

    // chunk size: largest power-of-two Gc whose scratch fits ws_size
    int Gc = 128;
    while (Gc > 1 && OFF_AS + (size_t)Gc * 288000 > ws_size) Gc >>= 1;
    float*          a_s = (float*)(ws + OFF_AS);
    float*          a_d = (float*)(ws + OFF_AS + (size_t)Gc * 16000);
    unsigned short* xp  = (unsigned short*)(ws + OFF_AS + (size_t)Gc * 32000);

    detect_dtype<<<1, 256, 0, stream>>>((const unsigned short*)d_in[0], flag);

    ConvArgs ca;
    const int sizes[11] = {2048000, 2048, 128, 128, 128, 32768, 16384, 256, 256, 512, 8};
    const int which[11] = {0, 2, 3, 4, 5, 6, 7, 8, 9, 10, 11};
    for (int i = 0; i < 11; ++i) {
        ca.src[i] = (const unsigned short*)d_in[which[i]];
        ca.n[i] = sizes[i];
    }
    convert_inputs<<<512, 256, 0, stream>>>(ca, flag, canon);

    hipMemsetAsync(pooled, 0, (size_t)kG * kHD * sizeof(float), stream);
    build_csr<<<1, 1024, 0, stream>>>(ei, row, colv);

    for (int g0 = 0; g0 < kG; g0 += Gc) {
        precompute<<<Gc * 16, 256, 0, stream>>>(cX, cWg, cAts, cAtd, xp, a_s, a_d, g0);
        gat_aggregate<<<(Gc * kN + 3) / 4, 256, 0, stream>>>(row, colv, xp, a_s, a_d,
                                                             cBg, pooled, g0, Gc);
    }
    lstm_head<<<kB, 256, 0, stream>>>((const float*)pooled, cWih, cWhh, cBih, cBhh,
                                      cWclf, cBclf, flag, d_out);
}

// Round 3
// 282.465 us; speedup vs baseline: 1.8255x; 1.8255x over previous
//
#include <hip/hip_runtime.h>
#include <hip/hip_bf16.h>
#include <stdint.h>

namespace {
constexpr int kB = 8, kT = 16, kN = 1000, kF = 16;
constexpr int kE = 16000;
constexpr int kH = 4, kHD = 128;
constexpr int kHL = 64, kOUT = 8;
constexpr int kG = kB * kT;
constexpr float kNeg = 0.2f;

// Canonical bf16 weights (x stays raw), element offsets:
constexpr size_t CX_WG   = 0;                       // 2048
constexpr size_t CX_ATS  = CX_WG   + 2048;          // 128
constexpr size_t CX_ATD  = CX_ATS  + 128;           // 128
constexpr size_t CX_BG   = CX_ATD  + 128;           // 128
constexpr size_t CX_WIH  = CX_BG   + 128;           // 32768
constexpr size_t CX_WHH  = CX_WIH  + 32768;         // 16384
constexpr size_t CX_BIH  = CX_WHH  + 16384;         // 256
constexpr size_t CX_BHH  = CX_BIH  + 256;           // 256
constexpr size_t CX_WCLF = CX_BHH  + 256;           // 512
constexpr size_t CX_BCLF = CX_WCLF + 512;           // 8
constexpr size_t CX_TOTAL = CX_BCLF + 8;            // 52,616 elements

// Workspace byte offsets (256-aligned)
constexpr size_t OFF_FLAG  = 0;
constexpr size_t OFF_ROW   = 256;
constexpr size_t OFF_COL   = 4352;
constexpr size_t OFF_POOL  = 68608;                  // float[kG*kHD]
constexpr size_t OFF_CANON = 134400;                 // bf16[CX_TOTAL] = 105232 B
constexpr size_t OFF_AS    = 239872;                 // per-chunk scratch
// per chunk of Gc graphs: a_s Gc*16000 B, a_d Gc*16000 B, xp Gc*256000 B
}

__device__ __forceinline__ float bf2f(unsigned short u) {
    return __uint_as_float(((uint32_t)u) << 16);
}
__device__ __forceinline__ float blo(uint32_t u) { return __uint_as_float(u << 16); }
__device__ __forceinline__ float bhi(uint32_t u) { return __uint_as_float(u & 0xffff0000u); }
__device__ __forceinline__ unsigned short f2bf(float f) {
    uint32_t u = __float_as_uint(f);
    uint32_t r = (u + 0x7fff + ((u >> 16) & 1)) >> 16;
    return (unsigned short)r;
}
__device__ __forceinline__ float sigm(float x) { return 1.f / (1.f + __expf(-x)); }

// ---------------------------------------------------------------------------
// Kernel 0: dtype detector (flag=1 means float tensors are fp32).
// ---------------------------------------------------------------------------
__global__ __launch_bounds__(256) void detect_dtype(const unsigned short* __restrict__ x,
                                                    int* __restrict__ flag) {
    __shared__ int cnt;
    if (threadIdx.x == 0) cnt = 0;
    __syncthreads();
    int local = 0;
    for (int i = threadIdx.x; i < 4096; i += 256) {
        unsigned short u = x[i];
        int ex = (u >> 7) & 0xff;
        if (u == 0 || (ex >= 97 && ex <= 143)) local++;
    }
    atomicAdd(&cnt, local);
    __syncthreads();
    if (threadIdx.x == 0) *flag = (cnt >= (4096 * 8) / 10) ? 0 : 1;
}

// ---------------------------------------------------------------------------
// Kernel 1: normalize the 10 weight tensors into canonical bf16.
// ---------------------------------------------------------------------------
struct ConvArgs {
    const unsigned short* src[10];
    int n[10];
};
__global__ __launch_bounds__(256) void convert_inputs(ConvArgs a,
                                                      const int* __restrict__ flag,
                                                      unsigned short* __restrict__ canon) {
    const int isf = *flag;
    const int stride = gridDim.x * blockDim.x;
    const int tid = blockIdx.x * blockDim.x + threadIdx.x;
    size_t base = 0;
    for (int s = 0; s < 10; ++s) {
        const int n = a.n[s];
        if (isf) {
            const float* fp = (const float*)a.src[s];
            for (int i = tid; i < n; i += stride) canon[base + i] = f2bf(fp[i]);
        } else {
            const unsigned short* sp = a.src[s];
            for (int i = tid; i < n; i += stride) canon[base + i] = sp[i];
        }
        base += (size_t)n;
    }
}

// ---------------------------------------------------------------------------
// Kernel 2: build CSR (edges sorted by dst). Single block, 1024 threads.
// ---------------------------------------------------------------------------
__global__ __launch_bounds__(1024) void build_csr(const int* __restrict__ ei,
                                                  int* __restrict__ row,
                                                  int* __restrict__ col) {
    __shared__ int cnt[1024];
    __shared__ int scan[1024];
    const int t = threadIdx.x;
    cnt[t] = 0;
    __syncthreads();
    const int* dst = ei + kE;
    for (int e = t; e < kE; e += 1024) atomicAdd(&cnt[dst[e]], 1);
    __syncthreads();
    scan[t] = cnt[t];
    __syncthreads();
    for (int s = 1; s < 1024; s <<= 1) {
        int v = (t >= s) ? scan[t - s] : 0;
        __syncthreads();
        scan[t] += v;
        __syncthreads();
    }
    if (t == 0) row[0] = 0;
    if (t < kN) row[t + 1] = scan[t];
    int excl = scan[t] - cnt[t];
    __syncthreads();
    cnt[t] = excl;
    __syncthreads();
    for (int e = t; e < kE; e += 1024) {
        int d0 = dst[e];
        int pos = atomicAdd(&cnt[d0], 1);
        col[pos] = ei[e];
    }
}

// ---------------------------------------------------------------------------
// Kernel 3: xp = x @ W_gat + attention scalars. XCD-swizzled: graph gl on
// XCD gl%8 (assumes round-robin blockIdx%8 -> XCD; perf heuristic only).
// ---------------------------------------------------------------------------
__global__ __launch_bounds__(256) void precompute(
        const void* __restrict__ xraw, const int* __restrict__ flag,
        const unsigned short* __restrict__ Wg,
        const unsigned short* __restrict__ atts,
        const unsigned short* __restrict__ attd,
        unsigned short* __restrict__ xp,
        float* __restrict__ a_s, float* __restrict__ a_d,
        int g0, int Gc) {
    __shared__ float Wl[kF * kHD];
    __shared__ float asl[kHD], adl[kHD];
    __shared__ float xr[64][kF];
    const int t = threadIdx.x;
    int gl, nb;
    if (Gc >= 8) {
        const int xcd = blockIdx.x & 7;
        const int j = blockIdx.x >> 3;
        const int gpx = Gc >> 3;
        gl = xcd + 8 * (j % gpx);
        nb = j / gpx;
    } else {
        gl = blockIdx.x >> 4;
        nb = blockIdx.x & 15;
    }
    const int gg = g0 + gl;
    const int isf = *flag;
    for (int i = t; i < kF * kHD; i += 256) Wl[i] = bf2f(Wg[i]);
    if (t < kHD) asl[t] = bf2f(atts[t]);
    else adl[t - kHD] = bf2f(attd[t - kHD]);
    const int n0 = nb * 64;
    const int nn = min(64, kN - n0);
    const size_t xbase = (size_t)gg * kN * kF + (size_t)n0 * kF;
    if (isf) {
        const float* xf = (const float*)xraw;
        for (int i = t; i < nn * kF; i += 256) xr[i / kF][i % kF] = xf[xbase + i];
    } else {
        const unsigned short* xb = (const unsigned short*)xraw;
        for (int i = t; i < nn * kF; i += 256) xr[i / kF][i % kF] = bf2f(xb[xbase + i]);
    }
    __syncthreads();

    const int c = t & 127;
    const int sub = t >> 7;
    const int h = c >> 5, d = c & 31;
    const float w_s = asl[c], w_d = adl[c];
    for (int ln = sub; ln < nn; ln += 2) {
        const int n = n0 + ln;
        float v = 0.f;
#pragma unroll
        for (int f = 0; f < kF; ++f) v += xr[ln][f] * Wl[f * kHD + c];
        xp[((size_t)gl * kN + n) * kHD + c] = f2bf(v);
        float vs = v * w_s, vd = v * w_d;
#pragma unroll
        for (int s = 16; s >= 1; s >>= 1) {
            vs += __shfl_xor(vs, s, 64);
            vd += __shfl_xor(vd, s, 64);
        }
        if (d == 0) {
            a_s[((size_t)gl * kN + n) * kH + h] = vs;
            a_d[((size_t)gl * kN + n) * kH + h] = vd;
        }
    }
}

// ---------------------------------------------------------------------------
// Kernel 4: GAT edge-softmax aggregation + relu + max-pool.
// One block = 40 nodes of ONE graph (10 iters x 4 waves). XCD-swizzled.
// Fast path (deg<=63): phase 1 lanes=edges (parallel logits, butterfly
// max/sum, p -> LDS); phase 2 lanes=channels (independent FMA gather).
// Block-level pool reduce -> 128 atomics per block.
// ---------------------------------------------------------------------------
__global__ __launch_bounds__(256) void gat_aggregate(
        const int* __restrict__ row, const int* __restrict__ col,
        const unsigned short* __restrict__ xp,
        const float* __restrict__ a_s, const float* __restrict__ a_d,
        const unsigned short* __restrict__ bg,
        unsigned int* __restrict__ pooled,
        int g0, int Gc) {
    __shared__ int   col_lds[4][64];
    __shared__ float p_lds[4][64][4];
    __shared__ float pm[4][kHD];

    const int w = threadIdx.x >> 6;
    const int lane = threadIdx.x & 63;
    int gl, blk;
    if (Gc >= 8) {
        const int xcd = blockIdx.x & 7;
        const int j = blockIdx.x >> 3;
        const int gpx = Gc >> 3;
        gl = xcd + 8 * (j % gpx);
        blk = j / gpx;                  // 0..24
    } else {
        gl = blockIdx.x / 25;
        blk = blockIdx.x % 25;
    }
    const size_t gn = (size_t)gl * kN;
    const uint32_t* xp32 = (const uint32_t*)(xp + gn * kHD);
    const int c0 = lane * 2;
    const int h = lane >> 4;
    const float bg0 = bf2f(bg[c0]), bg1 = bf2f(bg[c0 + 1]);
    float pmax0 = 0.f, pmax1 = 0.f;

    for (int it = 0; it < 10; ++it) {
        const int n = blk * 40 + it * 4 + w;
        const int r0 = row[n];
        const int deg = row[n + 1] - r0;
        float o0, o1;
        if (deg <= 63) {
            // ---- phase 1: lanes = edges (lane deg = self-loop) ----
            const int e = lane;
            const bool act = (e <= deg);
            int s = n;
            if (e < deg) s = col[r0 + e];
            float e0 = -3.0e38f, e1 = -3.0e38f, e2 = -3.0e38f, e3 = -3.0e38f;
            if (act) {
                const float4 av = ((const float4*)a_s)[gn + s];
                const float4 dv = ((const float4*)a_d)[gn + n];
                float t0 = av.x + dv.x, t1 = av.y + dv.y;
                float t2 = av.z + dv.z, t3 = av.w + dv.w;
                e0 = t0 > 0.f ? t0 : kNeg * t0;
                e1 = t1 > 0.f ? t1 : kNeg * t1;
                e2 = t2 > 0.f ? t2 : kNeg * t2;
                e3 = t3 > 0.f ? t3 : kNeg * t3;
            }
            float m0 = e0, m1 = e1, m2 = e2, m3 = e3;
#pragma unroll
            for (int sft = 1; sft < 64; sft <<= 1) {
                m0 = fmaxf(m0, __shfl_xor(m0, sft, 64));
                m1 = fmaxf(m1, __shfl_xor(m1, sft, 64));
                m2 = fmaxf(m2, __shfl_xor(m2, sft, 64));
                m3 = fmaxf(m3, __shfl_xor(m3, sft, 64));
            }
            float p0 = __expf(e0 - m0), p1 = __expf(e1 - m1);
            float p2 = __expf(e2 - m2), p3 = __expf(e3 - m3);
            float d0 = p0, d1 = p1, d2 = p2, d3 = p3;
#pragma unroll
            for (int sft = 1; sft < 64; sft <<= 1) {
                d0 += __shfl_xor(d0, sft, 64);
                d1 += __shfl_xor(d1, sft, 64);
                d2 += __shfl_xor(d2, sft, 64);
                d3 += __shfl_xor(d3, sft, 64);
            }
            if (act) {
                col_lds[w][e] = s;
                p_lds[w][e][0] = p0; p_lds[w][e][1] = p1;
                p_lds[w][e][2] = p2; p_lds[w][e][3] = p3;
            }
            // ---- phase 2: lanes = channels ----
            float accA = 0.f, accB = 0.f;
            for (int ee = 0; ee <= deg; ++ee) {
                const int ss = col_lds[w][ee];
                const float a = p_lds[w][ee][h];
                const uint32_t u = xp32[(size_t)ss * 64 + lane];
                accA += a * blo(u);
                accB += a * bhi(u);
            }
            const float dh = (h == 0) ? d0 : (h == 1) ? d1 : (h == 2) ? d2 : d3;
            const float inv = 1.f / dh;
            o0 = fmaxf(accA * inv + bg0, 0.f);
            o1 = fmaxf(accB * inv + bg1, 0.f);
        } else {
            // ---- rare slow path: serial online softmax (verified R2 code) ----
            const float ad = a_d[(gn + n) * kH + h];
            float es = a_s[(gn + n) * kH + h] + ad;
            es = es > 0.f ? es : kNeg * es;
            float m = es, den = 1.f;
            uint32_t u = xp32[(size_t)n * 64 + lane];
            float acc0 = blo(u), acc1 = bhi(u);
            const int r1 = r0 + deg;
            for (int ei = r0; ei < r1; ++ei) {
                const int s = col[ei];
                float ev = a_s[(gn + s) * kH + h] + ad;
                ev = ev > 0.f ? ev : kNeg * ev;
                const float nm = fmaxf(m, ev);
                const float sc = __expf(m - nm);
                const float p = __expf(ev - nm);
                const uint32_t us = xp32[(size_t)s * 64 + lane];
                den = den * sc + p;
                acc0 = acc0 * sc + p * blo(us);
                acc1 = acc1 * sc + p * bhi(us);
                m = nm;
            }
            const float inv = 1.f / den;
            o0 = fmaxf(acc0 * inv + bg0, 0.f);
            o1 = fmaxf(acc1 * inv + bg1, 0.f);
        }
        pmax0 = fmaxf(pmax0, o0);
        pmax1 = fmaxf(pmax1, o1);
    }
    pm[w][c0] = pmax0;
    pm[w][c0 + 1] = pmax1;
    __syncthreads();
    if (w == 0) {
        float v0 = fmaxf(fmaxf(pm[0][c0], pm[1][c0]), fmaxf(pm[2][c0], pm[3][c0]));
        float v1 = fmaxf(fmaxf(pm[0][c0 + 1], pm[1][c0 + 1]),
                         fmaxf(pm[2][c0 + 1], pm[3][c0 + 1]));
        const size_t gp = (size_t)(g0 + gl) * kHD;
        atomicMax(pooled + gp + c0, __float_as_uint(v0));
        atomicMax(pooled + gp + c0 + 1, __float_as_uint(v1));
    }
}

// ---------------------------------------------------------------------------
// Kernel 5: LSTM over T=16 + classifier. One block per batch row b.
// ---------------------------------------------------------------------------
__global__ __launch_bounds__(256) void lstm_head(
        const float* __restrict__ pooled,
        const unsigned short* __restrict__ Wih,
        const unsigned short* __restrict__ Whh,
        const unsigned short* __restrict__ bih,
        const unsigned short* __restrict__ bhh,
        const unsigned short* __restrict__ Wclf,
        const unsigned short* __restrict__ bclf,
        const int* __restrict__ flag,
        void* __restrict__ out) {
    const int b = blockIdx.x;
    const int r = threadIdx.x;
    __shared__ float xt[kHD];
    __shared__ float hs[kHL];
    __shared__ float gates[4 * kHL];

    uint32_t wih[64];
    const uint32_t* pw = (const uint32_t*)(Wih + (size_t)r * kHD);
#pragma unroll
    for (int j = 0; j < 64; ++j) wih[j] = pw[j];
    uint32_t whh[32];
    const uint32_t* ph = (const uint32_t*)(Whh + (size_t)r * kHL);
#pragma unroll
    for (int j = 0; j < 32; ++j) whh[j] = ph[j];
    const float bias = bf2f(bih[r]) + bf2f(bhh[r]);

    float c_st = 0.f;
    if (r < kHL) hs[r] = 0.f;
    __syncthreads();

    for (int t = 0; t < kT; ++t) {
        if (r < kHD) xt[r] = pooled[((size_t)b * kT + t) * kHD + r];
        __syncthreads();
        float a0 = 0.f, a1 = 0.f, a2 = 0.f, a3 = 0.f;
#pragma unroll
        for (int j = 0; j < 64; j += 4) {
            uint32_t u0 = wih[j], u1 = wih[j + 1], u2 = wih[j + 2], u3 = wih[j + 3];
            a0 += blo(u0) * xt[2 * j + 0] + bhi(u0) * xt[2 * j + 1];
            a1 += blo(u1) * xt[2 * j + 2] + bhi(u1) * xt[2 * j + 3];
            a2 += blo(u2) * xt[2 * j + 4] + bhi(u2) * xt[2 * j + 5];
            a3 += blo(u3) * xt[2 * j + 6] + bhi(u3) * xt[2 * j + 7];
        }
#pragma unroll
        for (int j = 0; j < 32; j += 4) {
            uint32_t u0 = whh[j], u1 = whh[j + 1], u2 = whh[j + 2], u3 = whh[j + 3];
            a0 += blo(u0) * hs[2 * j + 0] + bhi(u0) * hs[2 * j + 1];
            a1 += blo(u1) * hs[2 * j + 2] + bhi(u1) * hs[2 * j + 3];
            a2 += blo(u2) * hs[2 * j + 4] + bhi(u2) * hs[2 * j + 5];
            a3 += blo(u3) * hs[2 * j + 6] + bhi(u3) * hs[2 * j + 7];
        }
        gates[r] = bias + (a0 + a1) + (a2 + a3);
        __syncthreads();
        if (r < kHL) {
            const float iv = sigm(gates[r]);
            const float fv = sigm(gates[kHL + r]);
            const float gv = tanhf(gates[2 * kHL + r]);
            const float ov = sigm(gates[3 * kHL + r]);
            c_st = fv * c_st + iv * gv;
            hs[r] = ov * tanhf(c_st);
        }
        __syncthreads();
    }
    if (r < kOUT) {
        float acc = bf2f(bclf[r]);
#pragma unroll
        for (int k = 0; k < kHL; ++k) acc += hs[k] * bf2f(Wclf[r * kHL + k]);
        if (*flag) ((float*)out)[b * kOUT + r] = acc;
        else ((__hip_bfloat16*)out)[b * kOUT + r] = __float2bfloat16(acc);
    }
}

// ---------------------------------------------------------------------------
extern "C" void kernel_launch(void* const* d_in, const int* in_sizes, int n_in,
                              void* d_out, int out_size, void* d_ws, size_t ws_size,
                              hipStream_t stream) {
    const int* ei = (const int*)d_in[1];

    char* ws = (char*)d_ws;
    int*            flag   = (int*)(ws + OFF_FLAG);
    int*            row    = (int*)(ws + OFF_ROW);
    int*            colv   = (int*)(ws + OFF_COL);
    unsigned int*   pooled = (unsigned int*)(ws + OFF_POOL);
    unsigned short* canon  = (unsigned short*)(ws + OFF_CANON);

    unsigned short* cWg   = canon + CX_WG;
    unsigned short* cAts  = canon + CX_ATS;
    unsigned short* cAtd  = canon + CX_ATD;
    unsigned short* cBg   = canon + CX_BG;
    unsigned short* cWih  = canon + CX_WIH;
    unsigned short* cWhh  = canon + CX_WHH;
    unsigned short* cBih  = canon + CX_BIH;
    unsigned short* cBhh  = canon + CX_BHH;
    unsigned short* cWclf = canon + CX_WCLF;
    unsigned short* cBclf = canon + CX_BCLF;

    int Gc = 128;
    while (Gc > 1 && OFF_AS + (size_t)Gc * 288000 > ws_size) Gc >>= 1;
    float*          a_s = (float*)(ws + OFF_AS);
    float*          a_d = (float*)(ws + OFF_AS + (size_t)Gc * 16000);
    unsigned short* xp  = (unsigned short*)(ws + OFF_AS + (size_t)Gc * 32000);

    detect_dtype<<<1, 256, 0, stream>>>((const unsigned short*)d_in[0], flag);

    ConvArgs ca;
    const int sizes[10] = {2048, 128, 128, 128, 32768, 16384, 256, 256, 512, 8};
    const int which[10] = {2, 3, 4, 5, 6, 7, 8, 9, 10, 11};
    for (int i = 0; i < 10; ++i) {
        ca.src[i] = (const unsigned short*)d_in[which[i]];
        ca.n[i] = sizes[i];
    }
    convert_inputs<<<64, 256, 0, stream>>>(ca, flag, canon);

    hipMemsetAsync(pooled, 0, (size_t)kG * kHD * sizeof(float), stream);
    build_csr<<<1, 1024, 0, stream>>>(ei, row, colv);

    for (int g0 = 0; g0 < kG; g0 += Gc) {
        precompute<<<Gc * 16, 256, 0, stream>>>(d_in[0], flag, cWg, cAts, cAtd,
                                                xp, a_s, a_d, g0, Gc);
        gat_aggregate<<<Gc * 25, 256, 0, stream>>>(row, colv, xp, a_s, a_d,
                                                   cBg, pooled, g0, Gc);
    }
    lstm_head<<<kB, 256, 0, stream>>>((const float*)pooled, cWih, cWhh, cBih, cBhh,
                                      cWclf, cBclf, flag, d_out);
}

// Round 4
// 246.839 us; speedup vs baseline: 2.0890x; 1.1443x over previous
//
#include <hip/hip_runtime.h>
#include <hip/hip_bf16.h>
#include <stdint.h>

namespace {
constexpr int kB = 8, kT = 16, kN = 1000, kF = 16;
constexpr int kE = 16000;
constexpr int kH = 4, kHD = 128;
constexpr int kHL = 64, kOUT = 8;
constexpr int kG = kB * kT;
constexpr float kNeg = 0.2f;

// Canonical bf16 weights (x stays raw), element offsets:
constexpr size_t CX_WG   = 0;                       // 2048
constexpr size_t CX_ATS  = CX_WG   + 2048;
constexpr size_t CX_ATD  = CX_ATS  + 128;
constexpr size_t CX_BG   = CX_ATD  + 128;
constexpr size_t CX_WIH  = CX_BG   + 128;
constexpr size_t CX_WHH  = CX_WIH  + 32768;
constexpr size_t CX_BIH  = CX_WHH  + 16384;
constexpr size_t CX_BHH  = CX_BIH  + 256;
constexpr size_t CX_WCLF = CX_BHH  + 256;
constexpr size_t CX_BCLF = CX_WCLF + 512;
constexpr size_t CX_TOTAL = CX_BCLF + 8;            // 52,616 elements

// Workspace byte offsets (256-aligned)
constexpr size_t OFF_FLAG  = 0;
constexpr size_t OFF_ROW   = 256;
constexpr size_t OFF_COL   = 4352;
constexpr size_t OFF_POOL  = 68608;                  // float[kG*kHD]
constexpr size_t OFF_CANON = 134400;                 // bf16[CX_TOTAL]
constexpr size_t OFF_AS    = 239872;                 // per-chunk scratch
// per chunk of Gc graphs: a_s Gc*16000 B, a_d Gc*16000 B, xp Gc*256000 B
}

__device__ __forceinline__ float bf2f(unsigned short u) {
    return __uint_as_float(((uint32_t)u) << 16);
}
__device__ __forceinline__ float blo(uint32_t u) { return __uint_as_float(u << 16); }
__device__ __forceinline__ float bhi(uint32_t u) { return __uint_as_float(u & 0xffff0000u); }
__device__ __forceinline__ unsigned short f2bf(float f) {
    uint32_t u = __float_as_uint(f);
    uint32_t r = (u + 0x7fff + ((u >> 16) & 1)) >> 16;
    return (unsigned short)r;
}
__device__ __forceinline__ float sigm(float x) { return 1.f / (1.f + __expf(-x)); }

struct ConvArgs {
    const unsigned short* src[10];
    int n[10];
};

// ---------------------------------------------------------------------------
// Kernel 1 (fused setup, 3 blocks x 1024):
//  block 0: build CSR (dst-sorted edges)
//  block 1: dtype-detect then convert 10 weight tensors to canonical bf16
//  block 2: zero pooled
// ---------------------------------------------------------------------------
__global__ __launch_bounds__(1024) void setup(
        const unsigned short* __restrict__ x, const int* __restrict__ ei,
        ConvArgs ca, int* __restrict__ flag, int* __restrict__ row,
        int* __restrict__ col, unsigned int* __restrict__ pooled,
        unsigned short* __restrict__ canon) {
    const int t = threadIdx.x;
    if (blockIdx.x == 0) {
        // ---- CSR build ----
        __shared__ int cnt[1024];
        __shared__ int scan[1024];
        cnt[t] = 0;
        __syncthreads();
        const int* dst = ei + kE;
        for (int e = t; e < kE; e += 1024) atomicAdd(&cnt[dst[e]], 1);
        __syncthreads();
        scan[t] = cnt[t];
        __syncthreads();
        for (int s = 1; s < 1024; s <<= 1) {
            int v = (t >= s) ? scan[t - s] : 0;
            __syncthreads();
            scan[t] += v;
            __syncthreads();
        }
        if (t == 0) row[0] = 0;
        if (t < kN) row[t + 1] = scan[t];
        int excl = scan[t] - cnt[t];
        __syncthreads();
        cnt[t] = excl;
        __syncthreads();
        for (int e = t; e < kE; e += 1024) {
            int d0 = dst[e];
            int pos = atomicAdd(&cnt[d0], 1);
            col[pos] = ei[e];
        }
    } else if (blockIdx.x == 1) {
        // ---- dtype detect ----
        __shared__ int cnt1;
        __shared__ int isf_s;
        if (t == 0) cnt1 = 0;
        __syncthreads();
        int local = 0;
        for (int i = t; i < 4096; i += 1024) {
            unsigned short u = x[i];
            int ex = (u >> 7) & 0xff;
            if (u == 0 || (ex >= 97 && ex <= 143)) local++;
        }
        atomicAdd(&cnt1, local);
        __syncthreads();
        if (t == 0) {
            isf_s = (cnt1 >= (4096 * 8) / 10) ? 0 : 1;
            *flag = isf_s;
        }
        __syncthreads();
        // ---- convert weights to canonical bf16 ----
        const int isf = isf_s;
        size_t base = 0;
        for (int s = 0; s < 10; ++s) {
            const int n = ca.n[s];
            if (isf) {
                const float* fp = (const float*)ca.src[s];
                for (int i = t; i < n; i += 1024) canon[base + i] = f2bf(fp[i]);
            } else {
                const unsigned short* sp = ca.src[s];
                for (int i = t; i < n; i += 1024) canon[base + i] = sp[i];
            }
            base += (size_t)n;
        }
    } else {
        // ---- zero pooled ----
        for (int i = t; i < kG * kHD; i += 1024) pooled[i] = 0u;
    }
}

// ---------------------------------------------------------------------------
// Kernel 2: xp = x @ W_gat + attention scalars. XCD-swizzled.
// ---------------------------------------------------------------------------
__global__ __launch_bounds__(256) void precompute(
        const void* __restrict__ xraw, const int* __restrict__ flag,
        const unsigned short* __restrict__ Wg,
        const unsigned short* __restrict__ atts,
        const unsigned short* __restrict__ attd,
        unsigned short* __restrict__ xp,
        float* __restrict__ a_s, float* __restrict__ a_d,
        int g0, int Gc) {
    __shared__ float Wl[kF * kHD];
    __shared__ float asl[kHD], adl[kHD];
    __shared__ float xr[64][kF];
    const int t = threadIdx.x;
    int gl, nb;
    if (Gc >= 8) {
        const int xcd = blockIdx.x & 7;
        const int j = blockIdx.x >> 3;
        const int gpx = Gc >> 3;
        gl = xcd + 8 * (j % gpx);
        nb = j / gpx;
    } else {
        gl = blockIdx.x >> 4;
        nb = blockIdx.x & 15;
    }
    const int gg = g0 + gl;
    const int isf = *flag;
    for (int i = t; i < kF * kHD; i += 256) Wl[i] = bf2f(Wg[i]);
    if (t < kHD) asl[t] = bf2f(atts[t]);
    else adl[t - kHD] = bf2f(attd[t - kHD]);
    const int n0 = nb * 64;
    const int nn = min(64, kN - n0);
    const size_t xbase = (size_t)gg * kN * kF + (size_t)n0 * kF;
    if (isf) {
        const float* xf = (const float*)xraw;
        for (int i = t; i < nn * kF; i += 256) xr[i / kF][i % kF] = xf[xbase + i];
    } else {
        const unsigned short* xb = (const unsigned short*)xraw;
        for (int i = t; i < nn * kF; i += 256) xr[i / kF][i % kF] = bf2f(xb[xbase + i]);
    }
    __syncthreads();

    const int c = t & 127;
    const int sub = t >> 7;
    const int h = c >> 5, d = c & 31;
    const float w_s = asl[c], w_d = adl[c];
    for (int ln = sub; ln < nn; ln += 2) {
        const int n = n0 + ln;
        float v = 0.f;
#pragma unroll
        for (int f = 0; f < kF; ++f) v += xr[ln][f] * Wl[f * kHD + c];
        xp[((size_t)gl * kN + n) * kHD + c] = f2bf(v);
        float vs = v * w_s, vd = v * w_d;
#pragma unroll
        for (int s = 16; s >= 1; s >>= 1) {
            vs += __shfl_xor(vs, s, 64);
            vd += __shfl_xor(vd, s, 64);
        }
        if (d == 0) {
            a_s[((size_t)gl * kN + n) * kH + h] = vs;
            a_d[((size_t)gl * kN + n) * kH + h] = vd;
        }
    }
}

// ---------------------------------------------------------------------------
// Kernel 3: GAT edge-softmax aggregation + relu + max-pool.
// One block = 40 nodes of ONE graph (10 iters x 4 waves). XCD-swizzled.
// No softmax max-subtraction (logits ~N(0,2), exp safe in fp32); denominator
// accumulated in phase 2 as an extra channel (no shuffle reductions there).
// Phase 1: lanes = edges, compute exp(leakyrelu(logit)) for 4 heads -> LDS.
// Phase 2: 4 edge-subgroups x 16 lanes; each lane dwordx4 = 8 channels;
// 2-step xor-shuffle combine across subgroups at the end.
// ---------------------------------------------------------------------------
__global__ __launch_bounds__(256) void gat_aggregate(
        const int* __restrict__ row, const int* __restrict__ col,
        const unsigned short* __restrict__ xp,
        const float* __restrict__ a_s, const float* __restrict__ a_d,
        const unsigned short* __restrict__ bg,
        unsigned int* __restrict__ pooled,
        int g0, int Gc) {
    __shared__ int   col_lds[4][64];
    __shared__ float p_lds[4][64][4];
    __shared__ float pm[4][kHD];

    const int w = threadIdx.x >> 6;
    const int lane = threadIdx.x & 63;
    const int sub = lane >> 4;          // edge subgroup 0..3
    const int cl = lane & 15;           // channel-lane: channels cl*8 .. cl*8+7
    const int h = cl >> 2;              // head of those channels
    int gl, blk;
    if (Gc >= 8) {
        const int xcd = blockIdx.x & 7;
        const int j = blockIdx.x >> 3;
        const int gpx = Gc >> 3;
        gl = xcd + 8 * (j % gpx);
        blk = j / gpx;                  // 0..24
    } else {
        gl = blockIdx.x / 25;
        blk = blockIdx.x % 25;
    }
    const size_t gn = (size_t)gl * kN;
    const uint32_t* xpg = (const uint32_t*)(xp + gn * kHD);
    // bias for this lane's 8 channels
    const uint32_t* bg32 = (const uint32_t*)bg;
    float bgv[8];
#pragma unroll
    for (int j = 0; j < 4; ++j) {
        uint32_t u = bg32[cl * 4 + j];
        bgv[2 * j] = blo(u);
        bgv[2 * j + 1] = bhi(u);
    }
    float pool[8];
#pragma unroll
    for (int j = 0; j < 8; ++j) pool[j] = 0.f;

    for (int it = 0; it < 10; ++it) {
        const int n = blk * 40 + it * 4 + w;
        const int r0 = row[n];
        const int deg = row[n + 1] - r0;
        const int E = deg + 1;          // + self loop (index deg)
        float acc[8];
#pragma unroll
        for (int j = 0; j < 8; ++j) acc[j] = 0.f;
        float dh = 0.f;

        for (int base = 0; base < E; base += 64) {
            const int cnt = min(64, E - base);
            // ---- phase 1: lanes = edges ----
            if (lane < cnt) {
                const int eg = base + lane;
                const int s = (eg < deg) ? col[r0 + eg] : n;
                const float4 av = ((const float4*)a_s)[gn + s];
                const float4 dv = ((const float4*)a_d)[gn + n];
                float t0 = av.x + dv.x, t1 = av.y + dv.y;
                float t2 = av.z + dv.z, t3 = av.w + dv.w;
                t0 = t0 > 0.f ? t0 : kNeg * t0;
                t1 = t1 > 0.f ? t1 : kNeg * t1;
                t2 = t2 > 0.f ? t2 : kNeg * t2;
                t3 = t3 > 0.f ? t3 : kNeg * t3;
                col_lds[w][lane] = s;
                p_lds[w][lane][0] = __expf(t0);
                p_lds[w][lane][1] = __expf(t1);
                p_lds[w][lane][2] = __expf(t2);
                p_lds[w][lane][3] = __expf(t3);
            }
            // wave-synchronous: same wave wrote, same wave reads
            // ---- phase 2: 4 edges per iteration ----
            for (int e0 = 0; e0 < cnt; e0 += 4) {
                const int e = e0 + sub;
                if (e < cnt) {
                    const int ss = col_lds[w][e];
                    const float al = p_lds[w][e][h];
                    const uint4 u = *(const uint4*)(xpg + (size_t)ss * 64 + cl * 4);
                    acc[0] += al * blo(u.x); acc[1] += al * bhi(u.x);
                    acc[2] += al * blo(u.y); acc[3] += al * bhi(u.y);
                    acc[4] += al * blo(u.z); acc[5] += al * bhi(u.z);
                    acc[6] += al * blo(u.w); acc[7] += al * bhi(u.w);
                    dh += al;
                }
            }
        }
        // combine the 4 edge-subgroups (lanes xor 16, 32 hold same channels)
#pragma unroll
        for (int j = 0; j < 8; ++j) {
            acc[j] += __shfl_xor(acc[j], 16, 64);
            acc[j] += __shfl_xor(acc[j], 32, 64);
        }
        dh += __shfl_xor(dh, 16, 64);
        dh += __shfl_xor(dh, 32, 64);
        const float inv = 1.f / dh;
#pragma unroll
        for (int j = 0; j < 8; ++j) {
            const float o = acc[j] * inv + bgv[j];
            pool[j] = fmaxf(pool[j], o > 0.f ? o : 0.f);
        }
    }
    if (sub == 0) {
#pragma unroll
        for (int j = 0; j < 8; ++j) pm[w][cl * 8 + j] = pool[j];
    }
    __syncthreads();
    if (w == 0 && sub == 0) {
        const size_t gp = (size_t)(g0 + gl) * kHD;
#pragma unroll
        for (int j = 0; j < 8; ++j) {
            const int c = cl * 8 + j;
            float v = fmaxf(fmaxf(pm[0][c], pm[1][c]), fmaxf(pm[2][c], pm[3][c]));
            atomicMax(pooled + gp + c, __float_as_uint(v));
        }
    }
}

// ---------------------------------------------------------------------------
// Kernel 4: LSTM over T=16 + classifier. One block per batch row b.
// ---------------------------------------------------------------------------
__global__ __launch_bounds__(256) void lstm_head(
        const float* __restrict__ pooled,
        const unsigned short* __restrict__ Wih,
        const unsigned short* __restrict__ Whh,
        const unsigned short* __restrict__ bih,
        const unsigned short* __restrict__ bhh,
        const unsigned short* __restrict__ Wclf,
        const unsigned short* __restrict__ bclf,
        const int* __restrict__ flag,
        void* __restrict__ out) {
    const int b = blockIdx.x;
    const int r = threadIdx.x;
    __shared__ float xt[kHD];
    __shared__ float hs[kHL];
    __shared__ float gates[4 * kHL];

    uint32_t wih[64];
    const uint32_t* pw = (const uint32_t*)(Wih + (size_t)r * kHD);
#pragma unroll
    for (int j = 0; j < 64; ++j) wih[j] = pw[j];
    uint32_t whh[32];
    const uint32_t* ph = (const uint32_t*)(Whh + (size_t)r * kHL);
#pragma unroll
    for (int j = 0; j < 32; ++j) whh[j] = ph[j];
    const float bias = bf2f(bih[r]) + bf2f(bhh[r]);

    float c_st = 0.f;
    if (r < kHL) hs[r] = 0.f;
    __syncthreads();

    for (int t = 0; t < kT; ++t) {
        if (r < kHD) xt[r] = pooled[((size_t)b * kT + t) * kHD + r];
        __syncthreads();
        float a0 = 0.f, a1 = 0.f, a2 = 0.f, a3 = 0.f;
#pragma unroll
        for (int j = 0; j < 64; j += 4) {
            uint32_t u0 = wih[j], u1 = wih[j + 1], u2 = wih[j + 2], u3 = wih[j + 3];
            a0 += blo(u0) * xt[2 * j + 0] + bhi(u0) * xt[2 * j + 1];
            a1 += blo(u1) * xt[2 * j + 2] + bhi(u1) * xt[2 * j + 3];
            a2 += blo(u2) * xt[2 * j + 4] + bhi(u2) * xt[2 * j + 5];
            a3 += blo(u3) * xt[2 * j + 6] + bhi(u3) * xt[2 * j + 7];
        }
#pragma unroll
        for (int j = 0; j < 32; j += 4) {
            uint32_t u0 = whh[j], u1 = whh[j + 1], u2 = whh[j + 2], u3 = whh[j + 3];
            a0 += blo(u0) * hs[2 * j + 0] + bhi(u0) * hs[2 * j + 1];
            a1 += blo(u1) * hs[2 * j + 2] + bhi(u1) * hs[2 * j + 3];
            a2 += blo(u2) * hs[2 * j + 4] + bhi(u2) * hs[2 * j + 5];
            a3 += blo(u3) * hs[2 * j + 6] + bhi(u3) * hs[2 * j + 7];
        }
        gates[r] = bias + (a0 + a1) + (a2 + a3);
        __syncthreads();
        if (r < kHL) {
            const float iv = sigm(gates[r]);
            const float fv = sigm(gates[kHL + r]);
            const float gv = tanhf(gates[2 * kHL + r]);
            const float ov = sigm(gates[3 * kHL + r]);
            c_st = fv * c_st + iv * gv;
            hs[r] = ov * tanhf(c_st);
        }
        __syncthreads();
    }
    if (r < kOUT) {
        float acc = bf2f(bclf[r]);
#pragma unroll
        for (int k = 0; k < kHL; ++k) acc += hs[k] * bf2f(Wclf[r * kHL + k]);
        if (*flag) ((float*)out)[b * kOUT + r] = acc;
        else ((__hip_bfloat16*)out)[b * kOUT + r] = __float2bfloat16(acc);
    }
}

// ---------------------------------------------------------------------------
extern "C" void kernel_launch(void* const* d_in, const int* in_sizes, int n_in,
                              void* d_out, int out_size, void* d_ws, size_t ws_size,
                              hipStream_t stream) {
    const int* ei = (const int*)d_in[1];

    char* ws = (char*)d_ws;
    int*            flag   = (int*)(ws + OFF_FLAG);
    int*            row    = (int*)(ws + OFF_ROW);
    int*            colv   = (int*)(ws + OFF_COL);
    unsigned int*   pooled = (unsigned int*)(ws + OFF_POOL);
    unsigned short* canon  = (unsigned short*)(ws + OFF_CANON);

    unsigned short* cWg   = canon + CX_WG;
    unsigned short* cAts  = canon + CX_ATS;
    unsigned short* cAtd  = canon + CX_ATD;
    unsigned short* cBg   = canon + CX_BG;
    unsigned short* cWih  = canon + CX_WIH;
    unsigned short* cWhh  = canon + CX_WHH;
    unsigned short* cBih  = canon + CX_BIH;
    unsigned short* cBhh  = canon + CX_BHH;
    unsigned short* cWclf = canon + CX_WCLF;
    unsigned short* cBclf = canon + CX_BCLF;

    int Gc = 128;
    while (Gc > 1 && OFF_AS + (size_t)Gc * 288000 > ws_size) Gc >>= 1;
    float*          a_s = (float*)(ws + OFF_AS);
    float*          a_d = (float*)(ws + OFF_AS + (size_t)Gc * 16000);
    unsigned short* xp  = (unsigned short*)(ws + OFF_AS + (size_t)Gc * 32000);

    ConvArgs ca;
    const int sizes[10] = {2048, 128, 128, 128, 32768, 16384, 256, 256, 512, 8};
    const int which[10] = {2, 3, 4, 5, 6, 7, 8, 9, 10, 11};
    for (int i = 0; i < 10; ++i) {
        ca.src[i] = (const unsigned short*)d_in[which[i]];
        ca.n[i] = sizes[i];
    }

    setup<<<3, 1024, 0, stream>>>((const unsigned short*)d_in[0], ei, ca,
                                  flag, row, colv, pooled, canon);

    for (int g0 = 0; g0 < kG; g0 += Gc) {
        precompute<<<Gc * 16, 256, 0, stream>>>(d_in[0], flag, cWg, cAts, cAtd,
                                                xp, a_s, a_d, g0, Gc);
        gat_aggregate<<<Gc * 25, 256, 0, stream>>>(row, colv, xp, a_s, a_d,
                                                   cBg, pooled, g0, Gc);
    }
    lstm_head<<<kB, 256, 0, stream>>>((const float*)pooled, cWih, cWhh, cBih, cBhh,
                                      cWclf, cBclf, flag, d_out);
}